// Round 4
// baseline (906.756 us; speedup 1.0000x reference)
//
#include <hip/hip_runtime.h>
#include <stdint.h>

#define HH 512
#define WW 512
#define CIN 64
#define COUT 128
#define NB 4
#define HP 514          // padded rows: real y at y+1
#define WP 520          // padded cols: real x at x+1 (extra right pad for aligned staging)
#define STRIP 64        // x-sites per conv block
#define SCOLS 72        // staged cols per slab = 9 chunks x 8 cols
#define NCHUNK 9        // 1024B chunks per slab
#define SLAB_B (SCOLS * CIN * 2)   // 9216 B
#define YCHUNK 16

typedef __bf16 bf16x8 __attribute__((ext_vector_type(8)));
typedef float f32x4 __attribute__((ext_vector_type(4)));
typedef const __attribute__((address_space(1))) uint32_t guint_t;
typedef __attribute__((address_space(3))) uint32_t luint_t;

__device__ __forceinline__ unsigned short f2bf(float f) {
    union { float f; uint32_t u; } v; v.f = f;
    uint32_t u = v.u;
    u += 0x7fffu + ((u >> 16) & 1u);   // RNE
    return (unsigned short)(u >> 16);
}
__device__ __forceinline__ float bf2f(uint32_t u) {
    union { uint32_t u; float f; } v; v.u = u << 16;
    return v.f;
}

__global__ void zero_kernel(float4* __restrict__ p, long n4) {
    long i = (long)blockIdx.x * 256 + threadIdx.x;
    const long stride = (long)gridDim.x * 256;
    const float4 z = make_float4(0.f, 0.f, 0.f, 0.f);
    for (; i < n4; i += stride) p[i] = z;
}

// Wt2 layout: [(k>>3)][co][k&7] bf16, k = (ky*3+kx)*64 + ci  (576 x 128)
__global__ void wt_transform(const float* __restrict__ w, unsigned short* __restrict__ wt2) {
    int tid = blockIdx.x * 256 + threadIdx.x;
    if (tid >= COUT * 576) return;
    int co = tid / 576;
    int k  = tid - co * 576;
    int off = k >> 6;
    int ci  = k & 63;
    int ky = off / 3;
    int kx = off - ky * 3;
    float val = w[((co * CIN + ci) * 3 + ky) * 3 + kx];
    wt2[(size_t)(k >> 3) * (COUT * 8) + co * 8 + (k & 7)] = f2bf(val);
}

// Scatter-add into bf16 padded dense via packed-bf16x2 CAS.
// One lane per (point, channel-pair). dpad layout [B][HP][WP][CIN] bf16.
__global__ void scatter_kernel(const float* __restrict__ feat,
                               const int* __restrict__ coors,
                               uint32_t* __restrict__ dpad, int npts) {
    int t = blockIdx.x * 256 + threadIdx.x;
    int p = t >> 5;
    int c2 = t & 31;
    if (p >= npts) return;
    int b = coors[p * 3 + 0];
    int y = coors[p * 3 + 1];
    int x = coors[p * 3 + 2];
    uint32_t* wp = dpad + (((size_t)b * HP + (y + 1)) * WP + (x + 1)) * (CIN / 2) + c2;
    float ax = feat[(size_t)p * CIN + c2 * 2];
    float ay = feat[(size_t)p * CIN + c2 * 2 + 1];
    uint32_t old = *wp, assumed;
    do {
        assumed = old;
        uint32_t nv = (uint32_t)f2bf(bf2f(assumed & 0xffffu) + ax)
                    | ((uint32_t)f2bf(bf2f(assumed >> 16) + ay) << 16);
        old = atomicCAS(wp, assumed, nv);
    } while (old != assumed);
}

// Persistent-strip conv: block = (batch, 64-wide x-strip, 16-row y-chunk).
// 4-slot LDS ring of bf16 slabs staged via global_load_lds (linear dest,
// inverse-swizzled source; ds_read applies the same XOR -> conflict-free).
// 4 waves, each 32 sites x 64 co. A = dense sites (M), B = weights (N=co).
__global__ __launch_bounds__(256, 4) void conv_kernel(
        const __bf16* __restrict__ dpad,
        const __bf16* __restrict__ wt2,
        float* __restrict__ out) {
    __shared__ __align__(16) __bf16 ring[4 * SCOLS * CIN];

    const int bid = blockIdx.x;
    const int xs = bid & 7;
    const int yc = (bid >> 3) & 31;
    const int b  = bid >> 8;
    const int x0 = xs * STRIP;
    const int y0 = yc * YCHUNK;
    const int tid = threadIdx.x;
    const int wave = tid >> 6;
    const int lane = tid & 63;
    const int lhi = lane >> 4;
    const int llo = lane & 15;
    const int site_base = (wave & 1) * 32;
    const int co_base   = (wave >> 1) * 64;

    const char* gbase = (const char*)dpad;

    // issue async stage of pad row r into ring slot (no cvt, no VGPR roundtrip)
    auto stage = [&](int r, int slot) {
        const char* rowp = gbase + (((size_t)b * HP + r) * WP + x0) * (CIN * 2);
        char* lbase = ((char*)ring) + slot * SLAB_B;
        for (int c = wave; c < NCHUNK; c += 4) {
            int P = c * 1024 + lane * 16;                 // linear LDS byte pos
            int L = P ^ (((P >> 7) & 7) << 4);            // involutive inverse swizzle
            __builtin_amdgcn_global_load_lds(
                (guint_t*)(rowp + L),
                (luint_t*)(lbase + c * 1024),
                16, 0, 0);
        }
    };

    stage(y0 + 0, 0);
    stage(y0 + 1, 1);
    stage(y0 + 2, 2);
    __syncthreads();

    const size_t plane = (size_t)HH * WW;

    for (int s = 0; s < YCHUNK; ++s) {
        if (s < YCHUNK - 1) stage(y0 + s + 3, (s + 3) & 3);

        f32x4 acc[2][4];
        #pragma unroll
        for (int mt = 0; mt < 2; ++mt)
            #pragma unroll
            for (int nt = 0; nt < 4; ++nt)
                acc[mt][nt] = (f32x4){0.f, 0.f, 0.f, 0.f};

        #pragma unroll
        for (int off = 0; off < 9; ++off) {
            const int ky = off / 3;
            const int kx = off - ky * 3;
            const char* slot = (const char*)ring + (((s + ky) & 3) * SLAB_B);
            #pragma unroll
            for (int ch = 0; ch < 2; ++ch) {
                bf16x8 a[2];
                #pragma unroll
                for (int mt = 0; mt < 2; ++mt) {
                    int col = site_base + mt * 16 + llo + kx;
                    int eb = (ch * 64 + lhi * 16) ^ ((col & 7) << 4);  // swizzled read
                    a[mt] = *reinterpret_cast<const bf16x8*>(slot + col * 128 + eb);
                }
                const __bf16* bb = wt2 + (size_t)(off * 8 + ch * 4 + lhi) * (COUT * 8);
                #pragma unroll
                for (int nt = 0; nt < 4; ++nt) {
                    bf16x8 bw = *reinterpret_cast<const bf16x8*>(
                        &bb[(co_base + nt * 16 + llo) * 8]);
                    #pragma unroll
                    for (int mt = 0; mt < 2; ++mt)
                        acc[mt][nt] = __builtin_amdgcn_mfma_f32_16x16x32_bf16(
                            a[mt], bw, acc[mt][nt], 0, 0, 0);
                }
            }
        }
        __syncthreads();   // slot (s+3) now resident for next step

        // store output row y0+s AFTER the barrier: store drain overlaps next MFMA
        const int y = y0 + s;
        #pragma unroll
        for (int nt = 0; nt < 4; ++nt) {
            int co = co_base + nt * 16 + llo;
            float* orow = out + ((size_t)(b * COUT + co) * HH + y) * WW
                              + x0 + site_base + lhi * 4;
            #pragma unroll
            for (int mt = 0; mt < 2; ++mt)
                *reinterpret_cast<float4*>(&orow[mt * 16]) =
                    *reinterpret_cast<const float4*>(&acc[mt][nt]);
        }
    }
}

extern "C" void kernel_launch(void* const* d_in, const int* in_sizes, int n_in,
                              void* d_out, int out_size, void* d_ws, size_t ws_size,
                              hipStream_t stream) {
    const float* feat  = (const float*)d_in[0];
    const int*   coors = (const int*)d_in[1];
    const float* w     = (const float*)d_in[3];
    float* out = (float*)d_out;

    const size_t dpad_bytes = (size_t)NB * HP * WP * CIN * 2;   // 136,847,360 B
    __bf16* dpad = (__bf16*)d_ws;
    unsigned short* wt2 = (unsigned short*)((char*)d_ws + dpad_bytes);

    const int npts = in_sizes[0] / CIN; // 200000

    hipLaunchKernelGGL(zero_kernel, dim3(2048), dim3(256), 0, stream,
                       (float4*)dpad, (long)(dpad_bytes / 16));
    hipLaunchKernelGGL(wt_transform, dim3((COUT * 576 + 255) / 256), dim3(256), 0, stream,
                       w, wt2);
    hipLaunchKernelGGL(scatter_kernel, dim3((npts * 32 + 255) / 256), dim3(256), 0, stream,
                       feat, coors, (uint32_t*)dpad, npts);
    hipLaunchKernelGGL(conv_kernel, dim3(NB * (WW / STRIP) * (HH / YCHUNK)), dim3(256), 0, stream,
                       dpad, (const __bf16*)wt2, out);
}

// Round 5
// 265.019 us; speedup vs baseline: 3.4215x; 3.4215x over previous
//
#include <hip/hip_runtime.h>
#include <stdint.h>

#define HH 512
#define WW 512
#define CIN 64
#define COUT 128
#define NB 4
#define HP 514          // padded rows: real y at y+1
#define WP 520          // padded cols: real x at x+1
#define STRIP 128       // x-sites per conv block
#define SCOLS 136       // staged cols per slab (130 needed, padded to 17 chunks)
#define NCHUNK 17       // 1024B chunks per slab
#define SLAB_B (SCOLS * CIN * 2)   // 17408 B

typedef __bf16 bf16x8 __attribute__((ext_vector_type(8)));
typedef float f32x4 __attribute__((ext_vector_type(4)));
typedef const __attribute__((address_space(1))) uint32_t guint_t;
typedef __attribute__((address_space(3))) uint32_t luint_t;

__device__ __forceinline__ unsigned short f2bf(float f) {
    union { float f; uint32_t u; } v; v.f = f;
    uint32_t u = v.u;
    u += 0x7fffu + ((u >> 16) & 1u);   // RNE
    return (unsigned short)(u >> 16);
}
__device__ __forceinline__ float bf2f(uint32_t u) {
    union { uint32_t u; float f; } v; v.u = u << 16;
    return v.f;
}

__global__ void zero_kernel(float4* __restrict__ p, long n4) {
    long i = (long)blockIdx.x * 256 + threadIdx.x;
    const long stride = (long)gridDim.x * 256;
    const float4 z = make_float4(0.f, 0.f, 0.f, 0.f);
    for (; i < n4; i += stride) p[i] = z;
}

// Wt2 layout: [(k>>3)][co][k&7] bf16, k = (ky*3+kx)*64 + ci  (576 x 128)
__global__ void wt_transform(const float* __restrict__ w, unsigned short* __restrict__ wt2) {
    int tid = blockIdx.x * 256 + threadIdx.x;
    if (tid >= COUT * 576) return;
    int co = tid / 576;
    int k  = tid - co * 576;
    int off = k >> 6;
    int ci  = k & 63;
    int ky = off / 3;
    int kx = off - ky * 3;
    float val = w[((co * CIN + ci) * 3 + ky) * 3 + kx];
    wt2[(size_t)(k >> 3) * (COUT * 8) + co * 8 + (k & 7)] = f2bf(val);
}

// Scatter-add into bf16 padded dense via packed-bf16x2 CAS.
__global__ void scatter_kernel(const float* __restrict__ feat,
                               const int* __restrict__ coors,
                               uint32_t* __restrict__ dpad, int npts) {
    int t = blockIdx.x * 256 + threadIdx.x;
    int p = t >> 5;
    int c2 = t & 31;
    if (p >= npts) return;
    int b = coors[p * 3 + 0];
    int y = coors[p * 3 + 1];
    int x = coors[p * 3 + 2];
    uint32_t* wp = dpad + (((size_t)b * HP + (y + 1)) * WP + (x + 1)) * (CIN / 2) + c2;
    float ax = feat[(size_t)p * CIN + c2 * 2];
    float ay = feat[(size_t)p * CIN + c2 * 2 + 1];
    uint32_t old = *wp, assumed;
    do {
        assumed = old;
        uint32_t nv = (uint32_t)f2bf(bf2f(assumed & 0xffffu) + ax)
                    | ((uint32_t)f2bf(bf2f(assumed >> 16) + ay) << 16);
        old = atomicCAS(wp, assumed, nv);
    } while (old != assumed);
}

// One-shot conv block: (batch, output row y, 128-site strip), all 128 co.
// Stage 3 input rows via global_load_lds (linear LDS dest, inverse-swizzled
// source; ds_read applies the same XOR -> 2-way/free). 4 waves, each
// 64 sites x 64 co: 288 MFMA, 72 ds_read_b128, 72 global weight loads.
__global__ __launch_bounds__(256, 3) void conv_kernel(
        const __bf16* __restrict__ dpad,
        const __bf16* __restrict__ wt2,
        float* __restrict__ out) {
    __shared__ __align__(16) __bf16 lds[3 * SCOLS * CIN];

    const int bid = blockIdx.x;
    const int xs = bid & 3;
    const int y  = (bid >> 2) & 511;
    const int b  = bid >> 11;
    const int x0 = xs * STRIP;
    const int tid = threadIdx.x;
    const int wave = tid >> 6;
    const int lane = tid & 63;
    const int lhi = lane >> 4;
    const int llo = lane & 15;
    const int site_base = (wave & 1) * 64;
    const int co_base   = (wave >> 1) * 64;

    // stage 3 padded rows y, y+1, y+2 (= input rows y-1..y+1), cols x0..x0+135
    const char* gbase = (const char*)dpad;
    #pragma unroll
    for (int r = 0; r < 3; ++r) {
        const char* rowp = gbase + (((size_t)b * HP + (y + r)) * WP + x0) * (CIN * 2);
        char* lslab = ((char*)lds) + r * SLAB_B;
        #pragma unroll
        for (int i = 0; i < 5; ++i) {
            int c = wave + i * 4;
            if (c < NCHUNK) {
                int P = c * 1024 + lane * 16;
                int L = P ^ (((P >> 7) & 7) << 4);   // involution on bits 6:4
                __builtin_amdgcn_global_load_lds(
                    (guint_t*)(rowp + L), (luint_t*)(lslab + c * 1024), 16, 0, 0);
            }
        }
    }
    __syncthreads();

    f32x4 acc[4][4];
    #pragma unroll
    for (int mt = 0; mt < 4; ++mt)
        #pragma unroll
        for (int nt = 0; nt < 4; ++nt)
            acc[mt][nt] = (f32x4){0.f, 0.f, 0.f, 0.f};

    #pragma unroll
    for (int off = 0; off < 9; ++off) {
        const int ky = off / 3;
        const int kx = off - ky * 3;
        const char* slab = (const char*)lds + ky * SLAB_B;
        #pragma unroll
        for (int ch = 0; ch < 2; ++ch) {
            bf16x8 a[4];
            #pragma unroll
            for (int mt = 0; mt < 4; ++mt) {
                int col = site_base + mt * 16 + llo + kx;
                int eb = (ch * 64 + lhi * 16) ^ ((col & 7) << 4);
                a[mt] = *reinterpret_cast<const bf16x8*>(slab + col * 128 + eb);
            }
            const __bf16* bb = wt2 + (size_t)(off * 8 + ch * 4 + lhi) * (COUT * 8);
            #pragma unroll
            for (int nt = 0; nt < 4; ++nt) {
                bf16x8 bw = *reinterpret_cast<const bf16x8*>(
                    &bb[(co_base + nt * 16 + llo) * 8]);
                #pragma unroll
                for (int mt = 0; mt < 4; ++mt)
                    acc[mt][nt] = __builtin_amdgcn_mfma_f32_16x16x32_bf16(
                        a[mt], bw, acc[mt][nt], 0, 0, 0);
            }
        }
    }

    // D mapping: col(llo)=co, row(lhi*4+r)=site -> acc reg quad = 4 consecutive x
    #pragma unroll
    for (int nt = 0; nt < 4; ++nt) {
        int co = co_base + nt * 16 + llo;
        float* orow = out + ((size_t)(b * COUT + co) * HH + y) * WW
                          + x0 + site_base + lhi * 4;
        #pragma unroll
        for (int mt = 0; mt < 4; ++mt)
            __builtin_nontemporal_store(acc[mt][nt],
                reinterpret_cast<f32x4*>(&orow[mt * 16]));
    }
}

extern "C" void kernel_launch(void* const* d_in, const int* in_sizes, int n_in,
                              void* d_out, int out_size, void* d_ws, size_t ws_size,
                              hipStream_t stream) {
    const float* feat  = (const float*)d_in[0];
    const int*   coors = (const int*)d_in[1];
    const float* w     = (const float*)d_in[3];
    float* out = (float*)d_out;

    const size_t dpad_bytes = (size_t)NB * HP * WP * CIN * 2;   // ~137 MB
    __bf16* dpad = (__bf16*)d_ws;
    unsigned short* wt2 = (unsigned short*)((char*)d_ws + dpad_bytes);

    const int npts = in_sizes[0] / CIN; // 200000

    hipLaunchKernelGGL(zero_kernel, dim3(2048), dim3(256), 0, stream,
                       (float4*)dpad, (long)(dpad_bytes / 16));
    hipLaunchKernelGGL(wt_transform, dim3((COUT * 576 + 255) / 256), dim3(256), 0, stream,
                       w, wt2);
    hipLaunchKernelGGL(scatter_kernel, dim3((npts * 32 + 255) / 256), dim3(256), 0, stream,
                       feat, coors, (uint32_t*)dpad, npts);
    hipLaunchKernelGGL(conv_kernel, dim3(NB * 512 * (WW / STRIP)), dim3(256), 0, stream,
                       dpad, (const __bf16*)wt2, out);
}